// Round 5
// baseline (905.876 us; speedup 1.0000x reference)
//
#include <hip/hip_runtime.h>

#define NT 16384   // tokens
#define DM 4096    // d_model
#define NE 64      // experts
#define TPB 16     // tokens per block
#define NCH 16     // k-chunks of 256 (lane l owns k = 4l + 256c)

typedef __attribute__((address_space(3))) float lds_f;
typedef __attribute__((address_space(1))) const float glb_f;

__device__ __forceinline__ int bitrev6(int l) {
  return ((l & 1) << 5) | ((l & 2) << 3) | ((l & 4) << 1) |
         ((l & 8) >> 1) | ((l & 16) >> 3) | ((l & 32) >> 5);
}

// 6-level butterfly: after this, lane l holds the 64-lane total of a[bitrev6(l)]
// in a[0]. (R4-validated, absmax 0.)
__device__ __forceinline__ void butterfly64(float* a, int lane) {
#pragma unroll
  for (int s = 0; s < 6; ++s) {
    const int n = 32 >> s;
    const bool hi = (lane >> s) & 1;
#pragma unroll
    for (int i = 0; i < n; ++i) {
      const float mine  = hi ? a[i] : a[i + n];
      const float keep  = hi ? a[i + n] : a[i];
      const float other = __shfl_xor(mine, 1 << s, 64);
      a[i] = keep + other;
    }
  }
}

// Fused MoE gate. Block = 512 threads = 8 waves = 16 tokens x 64 experts
// (wave w owns experts [8w,8w+8) for all 16 tokens). x staged via
// global_load_lds into linear LDS (conflict-free both sides), W per-lane
// coalesced float4 double-buffered. f32 per-lane over 64 sequential k +
// f32 butterfly tree (validated accuracy scheme). Softmax/top-2 fused.
__launch_bounds__(512, 2)
__global__ void moe_gate(const float* __restrict__ x,
                         const float* __restrict__ W,
                         float* __restrict__ out,
                         float* __restrict__ bsum) {
  __shared__ float xs[2][TPB][256];    // 32 KiB, linear
  __shared__ float lg_s[TPB][NE + 1];  // 4.1 KiB
  __shared__ float esums[8][NE];       // 2 KiB

  const int tid  = threadIdx.x;
  const int lane = tid & 63;
  const int wv   = tid >> 6;
  const int wvu  = __builtin_amdgcn_readfirstlane(wv);
  const int blk  = blockIdx.x;
  const int tok0 = blk * TPB;

  // staging: wave w stages token rows 2w, 2w+1 of the 16-row x tile
  const float* xg0 = x + (size_t)(tok0 + 2 * wvu) * DM + lane * 4;
  const float* xg1 = xg0 + DM;
  float* l0 = &xs[0][2 * wvu][0];      // wave-uniform LDS dst (buf0)
  float* l1 = &xs[0][2 * wvu + 1][0];
  // W: per-lane coalesced, wave w -> experts [8w, 8w+8)
  const float* wp = W + (size_t)(wv * 8) * DM + lane * 4;

  float acc[TPB * 8];
#pragma unroll
  for (int i = 0; i < TPB * 8; ++i) acc[i] = 0.f;

  float4 wA[8], wB[8];

  // prologue: stage chunk 0 -> buf0, load wA(chunk 0)
  __builtin_amdgcn_global_load_lds((const glb_f*)xg0, (lds_f*)l0, 16, 0, 0);
  __builtin_amdgcn_global_load_lds((const glb_f*)xg1, (lds_f*)l1, 16, 0, 0);
#pragma unroll
  for (int j = 0; j < 8; ++j) wA[j] = *(const float4*)(wp + (size_t)j * DM);
  __syncthreads();

  const float* xb = &xs[0][0][0];
  for (int c = 0; c < NCH; c += 2) {
    // stage chunk c+1 -> buf1, prefetch wB(c+1)
    if (c + 1 < NCH) {
      __builtin_amdgcn_global_load_lds((const glb_f*)(xg0 + 256), (lds_f*)(l0 + TPB * 256), 16, 0, 0);
      __builtin_amdgcn_global_load_lds((const glb_f*)(xg1 + 256), (lds_f*)(l1 + TPB * 256), 16, 0, 0);
#pragma unroll
      for (int j = 0; j < 8; ++j) wB[j] = *(const float4*)(wp + (size_t)j * DM + 256);
    }
    // compute chunk c from buf0 with wA
#pragma unroll
    for (int t = 0; t < TPB; ++t) {
      const float4 xv = *(const float4*)(xb + t * 256 + lane * 4);
#pragma unroll
      for (int j = 0; j < 8; ++j) {
        float a = acc[t * 8 + j];
        a = fmaf(xv.x, wA[j].x, a);
        a = fmaf(xv.y, wA[j].y, a);
        a = fmaf(xv.z, wA[j].z, a);
        a = fmaf(xv.w, wA[j].w, a);
        acc[t * 8 + j] = a;
      }
    }
    __syncthreads();  // buf1 staged + all waves done reading buf0

    // stage chunk c+2 -> buf0, prefetch wA(c+2)
    if (c + 2 < NCH) {
      __builtin_amdgcn_global_load_lds((const glb_f*)(xg0 + 512), (lds_f*)l0, 16, 0, 0);
      __builtin_amdgcn_global_load_lds((const glb_f*)(xg1 + 512), (lds_f*)l1, 16, 0, 0);
#pragma unroll
      for (int j = 0; j < 8; ++j) wA[j] = *(const float4*)(wp + (size_t)j * DM + 512);
    }
    // compute chunk c+1 from buf1 with wB
    if (c + 1 < NCH) {
#pragma unroll
      for (int t = 0; t < TPB; ++t) {
        const float4 xv = *(const float4*)(xb + (TPB * 256) + t * 256 + lane * 4);
#pragma unroll
        for (int j = 0; j < 8; ++j) {
          float a = acc[t * 8 + j];
          a = fmaf(xv.x, wB[j].x, a);
          a = fmaf(xv.y, wB[j].y, a);
          a = fmaf(xv.z, wB[j].z, a);
          a = fmaf(xv.w, wB[j].w, a);
          acc[t * 8 + j] = a;
        }
      }
    }
    __syncthreads();
    xg0 += 512; xg1 += 512; wp += 512;
  }

  // cross-lane reduce: two 64-acc butterflies (tokens 0-7, 8-15)
  butterfly64(acc, lane);
  butterfly64(acc + 64, lane);
  const int a = bitrev6(lane);
  lg_s[(a >> 3)][wv * 8 + (a & 7)]     = acc[0];
  lg_s[8 + (a >> 3)][wv * 8 + (a & 7)] = acc[64];
  __syncthreads();

  // Epilogue (validated): wave wv handles tokens {2wv, 2wv+1}; lane <-> expert.
  float esum = 0.f;
#pragma unroll
  for (int ti = 0; ti < 2; ++ti) {
    const int t = 2 * wvu + ti;
    const float lg = lg_s[t][lane];

    float m = lg;
#pragma unroll
    for (int off = 32; off; off >>= 1) m = fmaxf(m, __shfl_xor(m, off, 64));
    const float p = __expf(lg - m);
    float Z = p;
#pragma unroll
    for (int off = 32; off; off >>= 1) Z += __shfl_xor(Z, off, 64);
    const float s = p / Z;
    esum += s;

    // top-1 (value desc, index asc — matches lax.top_k tie-break)
    float v1 = s; int i1 = lane;
#pragma unroll
    for (int off = 32; off; off >>= 1) {
      const float ov = __shfl_xor(v1, off, 64);
      const int   oi = __shfl_xor(i1, off, 64);
      if (ov > v1 || (ov == v1 && oi < i1)) { v1 = ov; i1 = oi; }
    }
    // top-2: mask winner (scores >= 0, so -1 acts as -inf)
    float sv = (lane == i1) ? -1.f : s;
    float v2 = sv; int i2 = lane;
#pragma unroll
    for (int off = 32; off; off >>= 1) {
      const float ov = __shfl_xor(v2, off, 64);
      const int   oi = __shfl_xor(i2, off, 64);
      if (ov > v2 || (ov == v2 && oi < i2)) { v2 = ov; i2 = oi; }
    }

    if (lane == 0) {
      const int gt = tok0 + t;
      const float inv = 1.f / (v1 + v2);
      out[2 * gt]              = v1 * inv;
      out[2 * gt + 1]          = v2 * inv;
      out[2 * NT + 2 * gt]     = (float)i1;
      out[2 * NT + 2 * gt + 1] = (float)i2;
    }
  }

  // per-block expert score sums (deterministic tree reduce, no atomics)
  esums[wvu][lane] = esum;
  __syncthreads();
  if (wvu == 0) {
    float tot = 0.f;
#pragma unroll
    for (int w = 0; w < 8; ++w) tot += esums[w][lane];
    bsum[blk * NE + lane] = tot;
  }
}

// Reduce 1024 per-block expert sums -> load balancing loss
__global__ void moe_gate_loss(const float* __restrict__ bsum,
                              float* __restrict__ out) {
  __shared__ float red[4][64];
  const int e = threadIdx.x & 63;
  const int g = threadIdx.x >> 6;
  float s = 0.f;
  for (int b = g; b < NT / TPB; b += 4) s += bsum[b * 64 + e];
  red[g][e] = s;
  __syncthreads();
  if (threadIdx.x < 64) {
    const float tot = red[0][e] + red[1][e] + red[2][e] + red[3][e];
    const float p = tot * (1.f / (float)NT);
    float term = p * logf(p + 1e-8f);
#pragma unroll
    for (int off = 32; off; off >>= 1) term += __shfl_xor(term, off, 64);
    if (e == 0) out[4 * NT] = term;  // out[65536]
  }
}

extern "C" void kernel_launch(void* const* d_in, const int* in_sizes, int n_in,
                              void* d_out, int out_size, void* d_ws, size_t ws_size,
                              hipStream_t stream) {
  const float* x = (const float*)d_in[0];   // [16384, 4096]
  const float* W = (const float*)d_in[1];   // [64, 4096]
  float* out = (float*)d_out;               // scores[32768] | idx[32768] | loss[1]
  float* bsum = (float*)d_ws;               // [1024][64] per-block expert sums

  hipLaunchKernelGGL(moe_gate, dim3(NT / TPB), dim3(512), 0, stream, x, W, out, bsum);
  hipLaunchKernelGGL(moe_gate_loss, dim3(1), dim3(256), 0, stream, bsum, out);
}